// Round 6
// baseline (1098.760 us; speedup 1.0000x reference)
//
#include <hip/hip_runtime.h>

#define Hdim 128
#define Idim 32
#define Bdim 4096
#define Sdim 512
#define ROWS 8       // 8 rows/block -> 512 blocks -> 2 independent blocks/CU
#define THREADS 512
#define HPAD 136     // 272B row stride: 16B-aligned so ds_read_b128 stays b128
#define XPAD 40      // 80B row stride, 16B aligned

typedef _Float16 half8 __attribute__((ext_vector_type(8)));
typedef _Float16 half4v __attribute__((ext_vector_type(4)));
typedef float f32x4 __attribute__((ext_vector_type(4)));

#define MFMA16(a, b, c) __builtin_amdgcn_mfma_f32_16x16x32_f16((a), (b), (c), 0, 0, 0)

// LDS-only barrier: no vmcnt drain (x loads covered by register deps, y stores never read).
#define BARRIER() asm volatile("s_waitcnt lgkmcnt(0)\n\ts_barrier" ::: "memory")

__device__ __forceinline__ float sigm(float x) {
    return __builtin_amdgcn_rcpf(1.0f + __builtin_amdgcn_exp2f(-1.44269504f * x));
}
__device__ __forceinline__ float tanh_fast(float x) {
    return 1.0f - 2.0f * __builtin_amdgcn_rcpf(1.0f + __builtin_amdgcn_exp2f(2.88539008f * x));
}

__device__ __forceinline__ half8 load8(const float* __restrict__ p) {
    float4 a = *(const float4*)p;
    float4 b = *(const float4*)(p + 4);
    half8 r;
    r[0] = (_Float16)a.x; r[1] = (_Float16)a.y; r[2] = (_Float16)a.z; r[3] = (_Float16)a.w;
    r[4] = (_Float16)b.x; r[5] = (_Float16)b.y; r[6] = (_Float16)b.z; r[7] = (_Float16)b.w;
    return r;
}

extern "C" __global__ __launch_bounds__(THREADS, 4)
void rnn_ae(const float* __restrict__ x, const float* __restrict__ h0,
            const float* __restrict__ eWih, const float* __restrict__ eWhh,
            const float* __restrict__ eBih, const float* __restrict__ eBhh,
            const float* __restrict__ dWih, const float* __restrict__ dWhh,
            const float* __restrict__ dBih, const float* __restrict__ dBhh,
            const float* __restrict__ linW, const float* __restrict__ linB,
            float* __restrict__ out)
{
    __shared__ _Float16 hlds[2][ROWS][HPAD];
    __shared__ _Float16 xlds[2][ROWS][XPAD];

    const int tid = threadIdx.x;
    const int w   = tid >> 6;            // wave 0..7 -> hidden-col slice [16w,16w+16)
    const int l   = tid & 63;
    const int cc  = l & 15;              // A-row / B-col / C-col lane field
    const int q   = l >> 4;              // quad 0..3
    const int kb  = q * 8;               // A/B k-base
    const int r0  = (q >> 1) * 2;        // acc slot base (dup-C: 2 useful elems/lane)
    const int rl0 = (q & 1) * 4 + (q >> 1) * 2;  // first owned batch row (0..7)
    const int ar7 = cc & 7;              // A-read row (C rows 8-15 duplicate 0-7)
    const int row0 = blockIdx.x * ROWS;
    const int j   = w * 16 + cc;         // this lane's hidden/gate column
    const int srow = tid >> 3;           // staging row (tid<64): 0..7
    const int sc4  = (tid & 7) << 2;     // staging col: 0,4,..,28

    const f32x4 zero = {0.f, 0.f, 0.f, 0.f};

    // ---------------- encoder weights -> registers (held for 512 steps) ----------------
    half8 bwi[3], bwh[3][4];
    float br, bz, bni, bnh;
    #pragma unroll
    for (int g = 0; g < 3; ++g) {
        int n = g * Hdim + j;                      // gate row in [3H] (r,z,n order)
        bwi[g] = load8(eWih + n * Idim + kb);      // B[k][n] = W[n][k]
        #pragma unroll
        for (int kk = 0; kk < 4; ++kk)
            bwh[g][kk] = load8(eWhh + n * Hdim + kk * 32 + kb);
    }
    br  = eBih[j] + eBhh[j];
    bz  = eBih[Hdim + j] + eBhh[Hdim + j];
    bni = eBih[2 * Hdim + j];
    bnh = eBhh[2 * Hdim + j];

    float hreg[2];
    #pragma unroll
    for (int r = 0; r < 2; ++r) {
        hreg[r] = h0[(size_t)(row0 + rl0 + r) * Hdim + j];
        hlds[0][rl0 + r][j] = (_Float16)hreg[r];
    }

    // x pipeline prologue: x[0] -> xlds[0]; x[1] -> regs (xv)
    float4 xv = {0.f, 0.f, 0.f, 0.f};
    if (tid < 64) {
        float4 v = *(const float4*)(x + ((size_t)(row0 + srow) * Sdim + 0) * Idim + sc4);
        half4v hv;
        hv[0] = (_Float16)v.x; hv[1] = (_Float16)v.y; hv[2] = (_Float16)v.z; hv[3] = (_Float16)v.w;
        *(half4v*)&xlds[0][srow][sc4] = hv;
        xv = *(const float4*)(x + ((size_t)(row0 + srow) * Sdim + 1) * Idim + sc4);
    }
    __syncthreads();

    // ---------------- encoder scan ----------------
    int cur = 0;
    for (int t = 0; t < Sdim; ++t) {
        half8 ax  = *(const half8*)&xlds[cur][ar7][kb];
        half8 ah0 = *(const half8*)&hlds[cur][ar7][kb];
        half8 ah1 = *(const half8*)&hlds[cur][ar7][32 + kb];
        half8 ah2 = *(const half8*)&hlds[cur][ar7][64 + kb];
        half8 ah3 = *(const half8*)&hlds[cur][ar7][96 + kb];

        if (tid < 64) {
            if (t + 1 < Sdim) {            // write x[t+1] (in regs since step t-1)
                half4v hv;
                hv[0] = (_Float16)xv.x; hv[1] = (_Float16)xv.y;
                hv[2] = (_Float16)xv.z; hv[3] = (_Float16)xv.w;
                *(half4v*)&xlds[cur ^ 1][srow][sc4] = hv;
            }
            if (t + 2 < Sdim)              // issue load of x[t+2]; lands during step t+1
                xv = *(const float4*)(x + ((size_t)(row0 + srow) * Sdim + (size_t)(t + 2)) * Idim + sc4);
        }

        f32x4 ar  = MFMA16(ax, bwi[0], zero);
        f32x4 az  = MFMA16(ax, bwi[1], zero);
        f32x4 ani = MFMA16(ax, bwi[2], zero);
        f32x4 anh = zero;
        ar  = MFMA16(ah0, bwh[0][0], ar);
        ar  = MFMA16(ah1, bwh[0][1], ar);
        ar  = MFMA16(ah2, bwh[0][2], ar);
        ar  = MFMA16(ah3, bwh[0][3], ar);
        az  = MFMA16(ah0, bwh[1][0], az);
        az  = MFMA16(ah1, bwh[1][1], az);
        az  = MFMA16(ah2, bwh[1][2], az);
        az  = MFMA16(ah3, bwh[1][3], az);
        anh = MFMA16(ah0, bwh[2][0], anh);
        anh = MFMA16(ah1, bwh[2][1], anh);
        anh = MFMA16(ah2, bwh[2][2], anh);
        anh = MFMA16(ah3, bwh[2][3], anh);

        #pragma unroll
        for (int r = 0; r < 2; ++r) {
            int   ai = r0 + r;                    // acc slot (dup rows carry valid data)
            float R  = sigm(ar[ai] + br);
            float Z  = sigm(az[ai] + bz);
            float Nn = tanh_fast(ani[ai] + bni + R * (anh[ai] + bnh)); // r gates only h-part
            float hn = Nn + Z * (hreg[r] - Nn);                        // (1-z)n + z h
            hreg[r] = hn;
            hlds[cur ^ 1][rl0 + r][j] = (_Float16)hn;
        }
        BARRIER();
        cur ^= 1;
    }

    // encoder final hidden -> output tail
    {
        const size_t HOFF = (size_t)Bdim * Sdim * Idim;
        #pragma unroll
        for (int r = 0; r < 2; ++r)
            out[HOFF + (size_t)(row0 + rl0 + r) * Hdim + j] = hreg[r];
    }

    // ---------------- decoder weights -> registers ----------------
    #pragma unroll
    for (int g = 0; g < 3; ++g) {
        int n = g * Hdim + j;
        bwi[g] = load8(dWih + n * Idim + kb);
        #pragma unroll
        for (int kk = 0; kk < 4; ++kk)
            bwh[g][kk] = load8(dWhh + n * Hdim + kk * 32 + kb);
    }
    br  = dBih[j] + dBhh[j];
    bz  = dBih[Hdim + j] + dBhh[Hdim + j];
    bni = dBih[2 * Hdim + j];
    bnh = dBhh[2 * Hdim + j];

    half8 blin[4];
    float lb = 0.f;
    {
        half8 hz;
        #pragma unroll
        for (int e = 0; e < 8; ++e) hz[e] = (_Float16)0.f;
        blin[0] = hz; blin[1] = hz; blin[2] = hz; blin[3] = hz;
    }
    const int ycol = w * 16 + cc;        // in-range only for w<2
    if (w < 2) {
        #pragma unroll
        for (int kk = 0; kk < 4; ++kk)
            blin[kk] = load8(linW + ycol * Hdim + kk * 32 + kb);
        lb = linB[ycol];
    }
    if (tid < 64) {                      // decoder seed: x[:,0,:] (h_enc already in hlds[0])
        float4 v = *(const float4*)(x + ((size_t)(row0 + srow) * Sdim + 0) * Idim + sc4);
        half4v hv;
        hv[0] = (_Float16)v.x; hv[1] = (_Float16)v.y; hv[2] = (_Float16)v.z; hv[3] = (_Float16)v.w;
        *(half4v*)&xlds[0][srow][sc4] = hv;
    }
    __syncthreads();

    // ---------------- decoder scan (autoregressive) ----------------
    cur = 0;
    for (int t = 0; t < Sdim; ++t) {
        half8 ax  = *(const half8*)&xlds[cur][ar7][kb];
        half8 ah0 = *(const half8*)&hlds[cur][ar7][kb];
        half8 ah1 = *(const half8*)&hlds[cur][ar7][32 + kb];
        half8 ah2 = *(const half8*)&hlds[cur][ar7][64 + kb];
        half8 ah3 = *(const half8*)&hlds[cur][ar7][96 + kb];

        f32x4 ar  = MFMA16(ax, bwi[0], zero);
        f32x4 az  = MFMA16(ax, bwi[1], zero);
        f32x4 ani = MFMA16(ax, bwi[2], zero);
        f32x4 anh = zero;
        ar  = MFMA16(ah0, bwh[0][0], ar);
        ar  = MFMA16(ah1, bwh[0][1], ar);
        ar  = MFMA16(ah2, bwh[0][2], ar);
        ar  = MFMA16(ah3, bwh[0][3], ar);
        az  = MFMA16(ah0, bwh[1][0], az);
        az  = MFMA16(ah1, bwh[1][1], az);
        az  = MFMA16(ah2, bwh[1][2], az);
        az  = MFMA16(ah3, bwh[1][3], az);
        anh = MFMA16(ah0, bwh[2][0], anh);
        anh = MFMA16(ah1, bwh[2][1], anh);
        anh = MFMA16(ah2, bwh[2][2], anh);
        anh = MFMA16(ah3, bwh[2][3], anh);

        #pragma unroll
        for (int r = 0; r < 2; ++r) {
            int   ai = r0 + r;
            float R  = sigm(ar[ai] + br);
            float Z  = sigm(az[ai] + bz);
            float Nn = tanh_fast(ani[ai] + bni + R * (anh[ai] + bnh));
            float hn = Nn + Z * (hreg[r] - Nn);
            hreg[r] = hn;
            hlds[cur ^ 1][rl0 + r][j] = (_Float16)hn;
        }
        BARRIER();         // h_{t+1} f16 visible for y-GEMM

        if (w < 2) {       // y = h_new @ linW^T + lb ; feed back as next x
            half8 p0 = *(const half8*)&hlds[cur ^ 1][ar7][kb];
            half8 p1 = *(const half8*)&hlds[cur ^ 1][ar7][32 + kb];
            half8 p2 = *(const half8*)&hlds[cur ^ 1][ar7][64 + kb];
            half8 p3 = *(const half8*)&hlds[cur ^ 1][ar7][96 + kb];
            f32x4 ay = MFMA16(p0, blin[0], zero);
            ay = MFMA16(p1, blin[1], ay);
            ay = MFMA16(p2, blin[2], ay);
            ay = MFMA16(p3, blin[3], ay);
            #pragma unroll
            for (int r = 0; r < 2; ++r) {
                float yv = ay[r0 + r] + lb;
                out[((size_t)(row0 + rl0 + r) * Sdim + (size_t)t) * Idim + ycol] = yv;
                xlds[cur ^ 1][rl0 + r][ycol] = (_Float16)yv;
            }
        }
        BARRIER();         // next step's x ready
        cur ^= 1;
    }
}

extern "C" void kernel_launch(void* const* d_in, const int* in_sizes, int n_in,
                              void* d_out, int out_size, void* d_ws, size_t ws_size,
                              hipStream_t stream) {
    (void)in_sizes; (void)n_in; (void)d_ws; (void)ws_size; (void)out_size;
    const float* x    = (const float*)d_in[0];
    const float* h0   = (const float*)d_in[1];
    const float* eWih = (const float*)d_in[2];
    const float* eWhh = (const float*)d_in[3];
    const float* eBih = (const float*)d_in[4];
    const float* eBhh = (const float*)d_in[5];
    const float* dWih = (const float*)d_in[6];
    const float* dWhh = (const float*)d_in[7];
    const float* dBih = (const float*)d_in[8];
    const float* dBhh = (const float*)d_in[9];
    const float* linW = (const float*)d_in[10];
    const float* linB = (const float*)d_in[11];
    rnn_ae<<<dim3(Bdim / ROWS), dim3(THREADS), 0, stream>>>(
        x, h0, eWih, eWhh, eBih, eBhh, dWih, dWhh, dBih, dBhh, linW, linB,
        (float*)d_out);
}

// Round 7
// 736.063 us; speedup vs baseline: 1.4928x; 1.4928x over previous
//
#include <hip/hip_runtime.h>

#define Hdim 128
#define Idim 32
#define Bdim 4096
#define Sdim 512
#define ROWS 16
#define THREADS 512
#define XPAD 40    // x row stride in halves (80B, 16B aligned)

typedef _Float16 half8 __attribute__((ext_vector_type(8)));
typedef _Float16 half4v __attribute__((ext_vector_type(4)));
typedef float f32x4 __attribute__((ext_vector_type(4)));

#define MFMA16(a, b, c) __builtin_amdgcn_mfma_f32_16x16x32_f16((a), (b), (c), 0, 0, 0)

// LDS-only barrier: no vmcnt drain (x loads covered by register deps, y stores never read).
#define BARRIER() asm volatile("s_waitcnt lgkmcnt(0)\n\ts_barrier" ::: "memory")

__device__ __forceinline__ float sigm(float x) {
    return __builtin_amdgcn_rcpf(1.0f + __builtin_amdgcn_exp2f(-1.44269504f * x));
}
__device__ __forceinline__ float tanh_fast(float x) {
    return 1.0f - 2.0f * __builtin_amdgcn_rcpf(1.0f + __builtin_amdgcn_exp2f(2.88539008f * x));
}

__device__ __forceinline__ half8 load8(const float* __restrict__ p) {
    float4 a = *(const float4*)p;
    float4 b = *(const float4*)(p + 4);
    half8 r;
    r[0] = (_Float16)a.x; r[1] = (_Float16)a.y; r[2] = (_Float16)a.z; r[3] = (_Float16)a.w;
    r[4] = (_Float16)b.x; r[5] = (_Float16)b.y; r[6] = (_Float16)b.z; r[7] = (_Float16)b.w;
    return r;
}
// f16(a[k] + b[k]) for 8 elements (combined decoder weights)
__device__ __forceinline__ half8 load8sum(const float* __restrict__ a, const float* __restrict__ b) {
    float4 a0 = *(const float4*)a,     a1 = *(const float4*)(a + 4);
    float4 b0 = *(const float4*)b,     b1 = *(const float4*)(b + 4);
    half8 r;
    r[0] = (_Float16)(a0.x + b0.x); r[1] = (_Float16)(a0.y + b0.y);
    r[2] = (_Float16)(a0.z + b0.z); r[3] = (_Float16)(a0.w + b0.w);
    r[4] = (_Float16)(a1.x + b1.x); r[5] = (_Float16)(a1.y + b1.y);
    r[6] = (_Float16)(a1.z + b1.z); r[7] = (_Float16)(a1.w + b1.w);
    return r;
}

// ---- prep: Wfold[n][h] = sum_i dWih[n][i]*linW[i][h]; bx[n] = sum_i dWih[n][i]*lin_b[i]
extern "C" __global__ void fold_k(const float* __restrict__ dWih, const float* __restrict__ linW,
                                  const float* __restrict__ linB, float* __restrict__ ws) {
    int idx = blockIdx.x * 256 + threadIdx.x;
    if (idx < 3 * Hdim * Hdim) {
        int n = idx >> 7, h = idx & 127;
        float s = 0.f;
        #pragma unroll
        for (int i = 0; i < Idim; ++i) s += dWih[n * Idim + i] * linW[i * Hdim + h];
        ws[idx] = s;
    }
    if (idx < 3 * Hdim) {
        float s = 0.f;
        #pragma unroll
        for (int i = 0; i < Idim; ++i) s += dWih[idx * Idim + i] * linB[i];
        ws[3 * Hdim * Hdim + idx] = s;
    }
}

extern "C" __global__ __launch_bounds__(THREADS, 2)
void rnn_ae(const float* __restrict__ x, const float* __restrict__ h0,
            const float* __restrict__ eWih, const float* __restrict__ eWhh,
            const float* __restrict__ eBih, const float* __restrict__ eBhh,
            const float* __restrict__ dWih, const float* __restrict__ dWhh,
            const float* __restrict__ dBih, const float* __restrict__ dBhh,
            const float* __restrict__ linW, const float* __restrict__ linB,
            const float* __restrict__ ws, float* __restrict__ out)
{
    // h stored in MFMA-A-fragment order: region m (k-tile), lane l reads halves [l*8, l*8+8)
    __shared__ _Float16 hfrag[2][4][512];
    __shared__ _Float16 xlds[2][ROWS][XPAD];

    const int tid = threadIdx.x;
    const int w   = tid >> 6;          // wave 0..7 -> hidden-col slice [16w,16w+16)
    const int l   = tid & 63;
    const int cc  = l & 15;            // A-row / B-col / C-col lane field
    const int cq  = l >> 4;            // quad 0..3
    const int kb  = cq * 8;            // A/B k-base
    const int rb  = cq * 4;            // C row-base (batch rows)
    const int row0 = blockIdx.x * ROWS;
    const int j   = w * 16 + cc;       // this lane's hidden/gate column
    const int srow = tid >> 3;         // staging row (tid<128)
    const int sc4  = (tid & 7) << 2;   // staging col
    const int wm   = j >> 5;                       // h-write frag region
    const int wbase = ((j & 31) >> 3) * 128 + (j & 7);  // h-write halves base in region

    const f32x4 zero = {0.f, 0.f, 0.f, 0.f};

    // ---------------- encoder weights -> registers ----------------
    half8 bwi[3], bwh[3][4];
    float br, bz, bni, bnh;
    #pragma unroll
    for (int g = 0; g < 3; ++g) {
        int n = g * Hdim + j;                      // gate row in [3H] (r,z,n order)
        bwi[g] = load8(eWih + n * Idim + kb);      // B[k][n] = W[n][k]
        #pragma unroll
        for (int kk = 0; kk < 4; ++kk)
            bwh[g][kk] = load8(eWhh + n * Hdim + kk * 32 + kb);
    }
    br  = eBih[j] + eBhh[j];
    bz  = eBih[Hdim + j] + eBhh[Hdim + j];
    bni = eBih[2 * Hdim + j];
    bnh = eBhh[2 * Hdim + j];

    float hreg[4];
    #pragma unroll
    for (int r = 0; r < 4; ++r) {
        hreg[r] = h0[(size_t)(row0 + rb + r) * Hdim + j];
        hfrag[0][wm][wbase + (rb + r) * 8] = (_Float16)hreg[r];
    }

    // x pipeline prologue: x[0] -> xlds[0]; x[1] -> regs (xv)
    float4 xv = {0.f, 0.f, 0.f, 0.f};
    if (tid < 128) {
        float4 v = *(const float4*)(x + ((size_t)(row0 + srow) * Sdim + 0) * Idim + sc4);
        half4v hv;
        hv[0] = (_Float16)v.x; hv[1] = (_Float16)v.y; hv[2] = (_Float16)v.z; hv[3] = (_Float16)v.w;
        *(half4v*)&xlds[0][srow][sc4] = hv;
        xv = *(const float4*)(x + ((size_t)(row0 + srow) * Sdim + 1) * Idim + sc4);
    }
    __syncthreads();

    // ---------------- encoder scan ----------------
    int cur = 0;
    for (int t = 0; t < Sdim; ++t) {
        half8 ax  = *(const half8*)&xlds[cur][cc][kb];
        half8 ah0 = *(const half8*)&hfrag[cur][0][l * 8];
        half8 ah1 = *(const half8*)&hfrag[cur][1][l * 8];
        half8 ah2 = *(const half8*)&hfrag[cur][2][l * 8];
        half8 ah3 = *(const half8*)&hfrag[cur][3][l * 8];

        if (tid < 128) {
            if (t + 1 < Sdim) {
                half4v hv;
                hv[0] = (_Float16)xv.x; hv[1] = (_Float16)xv.y;
                hv[2] = (_Float16)xv.z; hv[3] = (_Float16)xv.w;
                *(half4v*)&xlds[cur ^ 1][srow][sc4] = hv;
            }
            if (t + 2 < Sdim)
                xv = *(const float4*)(x + ((size_t)(row0 + srow) * Sdim + (size_t)(t + 2)) * Idim + sc4);
        }

        f32x4 ar  = MFMA16(ax, bwi[0], zero);
        f32x4 az  = MFMA16(ax, bwi[1], zero);
        f32x4 ani = MFMA16(ax, bwi[2], zero);
        f32x4 anh = zero;
        ar  = MFMA16(ah0, bwh[0][0], ar);
        ar  = MFMA16(ah1, bwh[0][1], ar);
        ar  = MFMA16(ah2, bwh[0][2], ar);
        ar  = MFMA16(ah3, bwh[0][3], ar);
        az  = MFMA16(ah0, bwh[1][0], az);
        az  = MFMA16(ah1, bwh[1][1], az);
        az  = MFMA16(ah2, bwh[1][2], az);
        az  = MFMA16(ah3, bwh[1][3], az);
        anh = MFMA16(ah0, bwh[2][0], anh);
        anh = MFMA16(ah1, bwh[2][1], anh);
        anh = MFMA16(ah2, bwh[2][2], anh);
        anh = MFMA16(ah3, bwh[2][3], anh);

        #pragma unroll
        for (int r = 0; r < 4; ++r) {
            float R  = sigm(ar[r] + br);
            float Z  = sigm(az[r] + bz);
            float Nn = tanh_fast(ani[r] + bni + R * (anh[r] + bnh)); // r gates only h-part
            float hn = Nn + Z * (hreg[r] - Nn);                      // (1-z)n + z h
            hreg[r] = hn;
            hfrag[cur ^ 1][wm][wbase + (rb + r) * 8] = (_Float16)hn;
        }
        BARRIER();
        cur ^= 1;
    }
    // cur == 0 here; hfrag[0] holds h_enc

    // encoder final hidden -> output tail
    {
        const size_t HOFF = (size_t)Bdim * Sdim * Idim;
        #pragma unroll
        for (int r = 0; r < 4; ++r)
            out[HOFF + (size_t)(row0 + rb + r) * Hdim + j] = hreg[r];
    }

    // ---------------- decoder step 0 (real x[:,0,:], unfolded weights) ----------------
    #pragma unroll
    for (int g = 0; g < 3; ++g) {
        int n = g * Hdim + j;
        bwi[g] = load8(dWih + n * Idim + kb);
        #pragma unroll
        for (int kk = 0; kk < 4; ++kk)
            bwh[g][kk] = load8(dWhh + n * Hdim + kk * 32 + kb);
    }
    const float bihr = dBih[j],            bhhr = dBhh[j];
    const float bihz = dBih[Hdim + j],     bhhz = dBhh[Hdim + j];
    const float bihn = dBih[2 * Hdim + j], bnhd = dBhh[2 * Hdim + j];

    if (tid < 128) {
        float4 v = *(const float4*)(x + ((size_t)(row0 + srow) * Sdim + 0) * Idim + sc4);
        half4v hv;
        hv[0] = (_Float16)v.x; hv[1] = (_Float16)v.y; hv[2] = (_Float16)v.z; hv[3] = (_Float16)v.w;
        *(half4v*)&xlds[0][srow][sc4] = hv;
    }
    __syncthreads();
    {
        half8 ax  = *(const half8*)&xlds[0][cc][kb];
        half8 ah0 = *(const half8*)&hfrag[0][0][l * 8];
        half8 ah1 = *(const half8*)&hfrag[0][1][l * 8];
        half8 ah2 = *(const half8*)&hfrag[0][2][l * 8];
        half8 ah3 = *(const half8*)&hfrag[0][3][l * 8];

        f32x4 ar  = MFMA16(ax, bwi[0], zero);
        f32x4 az  = MFMA16(ax, bwi[1], zero);
        f32x4 ani = MFMA16(ax, bwi[2], zero);
        f32x4 anh = zero;
        #pragma unroll
        for (int m = 0; m < 4; ++m) {
            half8 ah = (m == 0) ? ah0 : (m == 1) ? ah1 : (m == 2) ? ah2 : ah3;
            ar  = MFMA16(ah, bwh[0][m], ar);
            az  = MFMA16(ah, bwh[1][m], az);
            anh = MFMA16(ah, bwh[2][m], anh);
        }
        #pragma unroll
        for (int r = 0; r < 4; ++r) {
            float R  = sigm(ar[r] + bihr + bhhr);
            float Z  = sigm(az[r] + bihz + bhhz);
            float Nn = tanh_fast(ani[r] + bihn + R * (anh[r] + bnhd));
            float hn = Nn + Z * (hreg[r] - Nn);
            hreg[r] = hn;
            hfrag[1][wm][wbase + (rb + r) * 8] = (_Float16)hn;
        }
        BARRIER();
    }
    __builtin_amdgcn_sched_barrier(0);

    // ---------------- folded decoder weights ----------------
    // r,z: combined (Wfold + Whh); n: Wfold_n and Whh_n separate. bx = Wih@lin_b fold bias.
    half8 bcr[4], bcz[4], bfn[4], bhn[4];
    #pragma unroll
    for (int m = 0; m < 4; ++m) {
        int ko = m * 32 + kb;
        bcr[m] = load8sum(ws + (size_t)j * Hdim + ko,              dWhh + (size_t)j * Hdim + ko);
        bcz[m] = load8sum(ws + (size_t)(Hdim + j) * Hdim + ko,     dWhh + (size_t)(Hdim + j) * Hdim + ko);
        bfn[m] = load8(ws + (size_t)(2 * Hdim + j) * Hdim + ko);
        bhn[m] = load8(dWhh + (size_t)(2 * Hdim + j) * Hdim + ko);
    }
    const float* bx = ws + 3 * Hdim * Hdim;
    const float brd  = bihr + bhhr + bx[j];
    const float bzd  = bihz + bhhz + bx[Hdim + j];
    const float bnid = bihn + bx[2 * Hdim + j];

    half8 blin[4];
    float lb = 0.f;
    {
        half8 hz;
        #pragma unroll
        for (int e = 0; e < 8; ++e) hz[e] = (_Float16)0.f;
        blin[0] = hz; blin[1] = hz; blin[2] = hz; blin[3] = hz;
    }
    const int ycol = w * 16 + cc;      // in-range only for w<2
    if (w < 2) {
        #pragma unroll
        for (int kk = 0; kk < 4; ++kk)
            blin[kk] = load8(linW + ycol * Hdim + kk * 32 + kb);
        lb = linB[ycol];
    }

    // ---------------- decoder scan t=1..S-1 (folded; y one step delayed) ----------------
    cur = 1;
    for (int t = 1; t < Sdim; ++t) {
        half8 ah0 = *(const half8*)&hfrag[cur][0][l * 8];
        half8 ah1 = *(const half8*)&hfrag[cur][1][l * 8];
        half8 ah2 = *(const half8*)&hfrag[cur][2][l * 8];
        half8 ah3 = *(const half8*)&hfrag[cur][3][l * 8];

        if (w < 2) {       // y_{t-1} = h_t @ linW^T + lb  (same A-frags, off critical path)
            f32x4 ay = MFMA16(ah0, blin[0], zero);
            ay = MFMA16(ah1, blin[1], ay);
            ay = MFMA16(ah2, blin[2], ay);
            ay = MFMA16(ah3, blin[3], ay);
            #pragma unroll
            for (int r = 0; r < 4; ++r)
                out[((size_t)(row0 + rb + r) * Sdim + (size_t)(t - 1)) * Idim + ycol] = ay[r] + lb;
        }

        f32x4 ar  = MFMA16(ah0, bcr[0], zero);
        f32x4 az  = MFMA16(ah0, bcz[0], zero);
        f32x4 ani = MFMA16(ah0, bfn[0], zero);
        f32x4 anh = MFMA16(ah0, bhn[0], zero);
        ar  = MFMA16(ah1, bcr[1], ar);
        az  = MFMA16(ah1, bcz[1], az);
        ani = MFMA16(ah1, bfn[1], ani);
        anh = MFMA16(ah1, bhn[1], anh);
        ar  = MFMA16(ah2, bcr[2], ar);
        az  = MFMA16(ah2, bcz[2], az);
        ani = MFMA16(ah2, bfn[2], ani);
        anh = MFMA16(ah2, bhn[2], anh);
        ar  = MFMA16(ah3, bcr[3], ar);
        az  = MFMA16(ah3, bcz[3], az);
        ani = MFMA16(ah3, bfn[3], ani);
        anh = MFMA16(ah3, bhn[3], anh);

        #pragma unroll
        for (int r = 0; r < 4; ++r) {
            float R  = sigm(ar[r] + brd);
            float Z  = sigm(az[r] + bzd);
            float Nn = tanh_fast(ani[r] + bnid + R * (anh[r] + bnhd));
            float hn = Nn + Z * (hreg[r] - Nn);
            hreg[r] = hn;
            hfrag[cur ^ 1][wm][wbase + (rb + r) * 8] = (_Float16)hn;
        }
        BARRIER();
        cur ^= 1;
    }

    // final y_{S-1} from last h
    if (w < 2) {
        half8 ah0 = *(const half8*)&hfrag[cur][0][l * 8];
        half8 ah1 = *(const half8*)&hfrag[cur][1][l * 8];
        half8 ah2 = *(const half8*)&hfrag[cur][2][l * 8];
        half8 ah3 = *(const half8*)&hfrag[cur][3][l * 8];
        f32x4 ay = MFMA16(ah0, blin[0], zero);
        ay = MFMA16(ah1, blin[1], ay);
        ay = MFMA16(ah2, blin[2], ay);
        ay = MFMA16(ah3, blin[3], ay);
        #pragma unroll
        for (int r = 0; r < 4; ++r)
            out[((size_t)(row0 + rb + r) * Sdim + (size_t)(Sdim - 1)) * Idim + ycol] = ay[r] + lb;
    }
}

extern "C" void kernel_launch(void* const* d_in, const int* in_sizes, int n_in,
                              void* d_out, int out_size, void* d_ws, size_t ws_size,
                              hipStream_t stream) {
    (void)in_sizes; (void)n_in; (void)ws_size; (void)out_size;
    const float* x    = (const float*)d_in[0];
    const float* h0   = (const float*)d_in[1];
    const float* eWih = (const float*)d_in[2];
    const float* eWhh = (const float*)d_in[3];
    const float* eBih = (const float*)d_in[4];
    const float* eBhh = (const float*)d_in[5];
    const float* dWih = (const float*)d_in[6];
    const float* dWhh = (const float*)d_in[7];
    const float* dBih = (const float*)d_in[8];
    const float* dBhh = (const float*)d_in[9];
    const float* linW = (const float*)d_in[10];
    const float* linB = (const float*)d_in[11];
    float* ws = (float*)d_ws;

    fold_k<<<dim3((3 * Hdim * Hdim + 255) / 256), dim3(256), 0, stream>>>(dWih, linW, linB, ws);
    rnn_ae<<<dim3(Bdim / ROWS), dim3(THREADS), 0, stream>>>(
        x, h0, eWih, eWhh, eBih, eBhh, dWih, dWhh, dBih, dBhh, linW, linB,
        ws, (float*)d_out);
}

// Round 8
// 681.641 us; speedup vs baseline: 1.6119x; 1.0798x over previous
//
#include <hip/hip_runtime.h>

#define Hdim 128
#define Idim 32
#define Bdim 4096
#define Sdim 512
#define ROWS 16
#define THREADS 512
#define XPAD 40    // x row stride in halves (80B, 16B aligned)

#define KR (-1.44269504f)   // r,z prescale: Er = exp2(KR*arg) = e^-arg
#define KN (2.88539008f)    // n prescale:   En = exp2(KN*arg) = e^(2*arg)

typedef _Float16 half8 __attribute__((ext_vector_type(8)));
typedef _Float16 half4v __attribute__((ext_vector_type(4)));
typedef float f32x4 __attribute__((ext_vector_type(4)));

#define MFMA16(a, b, c) __builtin_amdgcn_mfma_f32_16x16x32_f16((a), (b), (c), 0, 0, 0)

// LDS-only barrier: no vmcnt drain (x loads covered by register deps, y stores never read).
#define BARRIER() asm volatile("s_waitcnt lgkmcnt(0)\n\ts_barrier" ::: "memory")

// Fused GRU update, 5 transcendentals (exp2 args pre-scaled into the accumulators):
// a_r = KR*(i_r+h_r+b), a_z = KR*(i_z+h_z+b), a_i = KN*(i_n+bi), a_h = KN*(h_n+bh)
__device__ __forceinline__ float gru_h(float a_r, float a_z, float a_i, float a_h, float h) {
    float Er = __builtin_amdgcn_exp2f(a_r);               // e^-rarg
    float R  = __builtin_amdgcn_rcpf(1.0f + Er);          // sigmoid(rarg)
    float v  = fminf(fmaf(R, a_h, a_i), 63.0f);           // KN*(i_n + R*h_n), clamped
    float En = __builtin_amdgcn_exp2f(v);                 // e^(2*narg)
    float Ez = __builtin_amdgcn_exp2f(fminf(a_z, 63.0f)); // e^-zarg
    float num = fmaf(En, Ez + h, h - Ez);                 // En(Ez+h) + (h-Ez)
    float den = (1.0f + Ez) * (1.0f + En);
    return num * __builtin_amdgcn_rcpf(den);              // (1-z)*tanh(narg) + z*h
}

__device__ __forceinline__ half8 load8s(const float* __restrict__ p, float s) {
    float4 a = *(const float4*)p;
    float4 b = *(const float4*)(p + 4);
    half8 r;
    r[0] = (_Float16)(a.x * s); r[1] = (_Float16)(a.y * s);
    r[2] = (_Float16)(a.z * s); r[3] = (_Float16)(a.w * s);
    r[4] = (_Float16)(b.x * s); r[5] = (_Float16)(b.y * s);
    r[6] = (_Float16)(b.z * s); r[7] = (_Float16)(b.w * s);
    return r;
}
// f16(s*(a[k] + b[k])) for 8 elements (combined decoder weights)
__device__ __forceinline__ half8 load8sum(const float* __restrict__ a, const float* __restrict__ b, float s) {
    float4 a0 = *(const float4*)a,     a1 = *(const float4*)(a + 4);
    float4 b0 = *(const float4*)b,     b1 = *(const float4*)(b + 4);
    half8 r;
    r[0] = (_Float16)((a0.x + b0.x) * s); r[1] = (_Float16)((a0.y + b0.y) * s);
    r[2] = (_Float16)((a0.z + b0.z) * s); r[3] = (_Float16)((a0.w + b0.w) * s);
    r[4] = (_Float16)((a1.x + b1.x) * s); r[5] = (_Float16)((a1.y + b1.y) * s);
    r[6] = (_Float16)((a1.z + b1.z) * s); r[7] = (_Float16)((a1.w + b1.w) * s);
    return r;
}

// ---- prep: Wfold[n][h] = sum_i dWih[n][i]*linW[i][h]; bx[n] = sum_i dWih[n][i]*lin_b[i]
extern "C" __global__ void fold_k(const float* __restrict__ dWih, const float* __restrict__ linW,
                                  const float* __restrict__ linB, float* __restrict__ ws) {
    int idx = blockIdx.x * 256 + threadIdx.x;
    if (idx < 3 * Hdim * Hdim) {
        int n = idx >> 7, h = idx & 127;
        float s = 0.f;
        #pragma unroll
        for (int i = 0; i < Idim; ++i) s += dWih[n * Idim + i] * linW[i * Hdim + h];
        ws[idx] = s;
    }
    if (idx < 3 * Hdim) {
        float s = 0.f;
        #pragma unroll
        for (int i = 0; i < Idim; ++i) s += dWih[idx * Idim + i] * linB[i];
        ws[3 * Hdim * Hdim + idx] = s;
    }
}

extern "C" __global__ __launch_bounds__(THREADS, 2)
void rnn_ae(const float* __restrict__ x, const float* __restrict__ h0,
            const float* __restrict__ eWih, const float* __restrict__ eWhh,
            const float* __restrict__ eBih, const float* __restrict__ eBhh,
            const float* __restrict__ dWih, const float* __restrict__ dWhh,
            const float* __restrict__ dBih, const float* __restrict__ dBhh,
            const float* __restrict__ linW, const float* __restrict__ linB,
            const float* __restrict__ ws, float* __restrict__ out)
{
    // h stored in MFMA-A-fragment order: region m (k-tile), lane l reads halves [l*8, l*8+8)
    __shared__ _Float16 hfrag[2][4][512];
    __shared__ _Float16 xlds[2][ROWS][XPAD];

    const int tid = threadIdx.x;
    const int w   = tid >> 6;          // wave 0..7 -> hidden-col slice [16w,16w+16)
    const int l   = tid & 63;
    const int cc  = l & 15;            // A-row / B-col / C-col lane field
    const int cq  = l >> 4;            // quad 0..3
    const int kb  = cq * 8;            // A/B k-base
    const int rb  = cq * 4;            // C row-base (batch rows)
    const int row0 = blockIdx.x * ROWS;
    const int j   = w * 16 + cc;       // this lane's hidden/gate column
    const int srow = tid >> 3;         // staging row (tid<128)
    const int sc4  = (tid & 7) << 2;   // staging col
    const int wm   = j >> 5;                            // h-write frag region
    const int wbase = ((j & 31) >> 3) * 128 + (j & 7);  // h-write halves base in region

    const f32x4 zero = {0.f, 0.f, 0.f, 0.f};

    // ---------------- encoder weights -> registers (prescaled) ----------------
    half8 bwi[3], bwh[3][4];
    #pragma unroll
    for (int g = 0; g < 3; ++g) {
        float s = (g == 2) ? KN : KR;
        int n = g * Hdim + j;                          // gate row in [3H] (r,z,n order)
        bwi[g] = load8s(eWih + n * Idim + kb, s);      // B[k][n] = W[n][k]
        #pragma unroll
        for (int kk = 0; kk < 4; ++kk)
            bwh[g][kk] = load8s(eWhh + n * Hdim + kk * 32 + kb, s);
    }
    // bias-in-accumulator vectors (per-lane scalar broadcast to 4 acc slots)
    float brv  = KR * (eBih[j] + eBhh[j]);
    float bzv  = KR * (eBih[Hdim + j] + eBhh[Hdim + j]);
    float bniv = KN * eBih[2 * Hdim + j];
    float bnhv = KN * eBhh[2 * Hdim + j];
    f32x4 arB = {brv, brv, brv, brv};
    f32x4 azB = {bzv, bzv, bzv, bzv};
    f32x4 aiB = {bniv, bniv, bniv, bniv};
    f32x4 ahB = {bnhv, bnhv, bnhv, bnhv};

    float hreg[4];
    #pragma unroll
    for (int r = 0; r < 4; ++r) {
        hreg[r] = h0[(size_t)(row0 + rb + r) * Hdim + j];
        hfrag[0][wm][wbase + (rb + r) * 8] = (_Float16)hreg[r];
    }

    // x pipeline prologue: x[0] -> xlds[0]; x[1] -> regs (xv)
    float4 xv = {0.f, 0.f, 0.f, 0.f};
    if (tid < 128) {
        float4 v = *(const float4*)(x + ((size_t)(row0 + srow) * Sdim + 0) * Idim + sc4);
        half4v hv;
        hv[0] = (_Float16)v.x; hv[1] = (_Float16)v.y; hv[2] = (_Float16)v.z; hv[3] = (_Float16)v.w;
        *(half4v*)&xlds[0][srow][sc4] = hv;
        xv = *(const float4*)(x + ((size_t)(row0 + srow) * Sdim + 1) * Idim + sc4);
    }
    __syncthreads();

    // ---------------- encoder scan ----------------
    int cur = 0;
    for (int t = 0; t < Sdim; ++t) {
        half8 ax  = *(const half8*)&xlds[cur][cc][kb];
        half8 ah0 = *(const half8*)&hfrag[cur][0][l * 8];
        half8 ah1 = *(const half8*)&hfrag[cur][1][l * 8];
        half8 ah2 = *(const half8*)&hfrag[cur][2][l * 8];
        half8 ah3 = *(const half8*)&hfrag[cur][3][l * 8];

        if (tid < 128) {
            if (t + 1 < Sdim) {
                half4v hv;
                hv[0] = (_Float16)xv.x; hv[1] = (_Float16)xv.y;
                hv[2] = (_Float16)xv.z; hv[3] = (_Float16)xv.w;
                *(half4v*)&xlds[cur ^ 1][srow][sc4] = hv;
            }
            if (t + 2 < Sdim)
                xv = *(const float4*)(x + ((size_t)(row0 + srow) * Sdim + (size_t)(t + 2)) * Idim + sc4);
        }

        f32x4 ar  = MFMA16(ax, bwi[0], arB);
        f32x4 az  = MFMA16(ax, bwi[1], azB);
        f32x4 ani = MFMA16(ax, bwi[2], aiB);
        f32x4 anh = ahB;
        ar  = MFMA16(ah0, bwh[0][0], ar);
        ar  = MFMA16(ah1, bwh[0][1], ar);
        ar  = MFMA16(ah2, bwh[0][2], ar);
        ar  = MFMA16(ah3, bwh[0][3], ar);
        az  = MFMA16(ah0, bwh[1][0], az);
        az  = MFMA16(ah1, bwh[1][1], az);
        az  = MFMA16(ah2, bwh[1][2], az);
        az  = MFMA16(ah3, bwh[1][3], az);
        anh = MFMA16(ah0, bwh[2][0], anh);
        anh = MFMA16(ah1, bwh[2][1], anh);
        anh = MFMA16(ah2, bwh[2][2], anh);
        anh = MFMA16(ah3, bwh[2][3], anh);

        #pragma unroll
        for (int r = 0; r < 4; ++r) {
            float hn = gru_h(ar[r], az[r], ani[r], anh[r], hreg[r]);
            hreg[r] = hn;
            hfrag[cur ^ 1][wm][wbase + (rb + r) * 8] = (_Float16)hn;
        }
        BARRIER();
        cur ^= 1;
    }
    // cur == 0 here; hfrag[0] holds h_enc

    // encoder final hidden -> output tail
    {
        const size_t HOFF = (size_t)Bdim * Sdim * Idim;
        #pragma unroll
        for (int r = 0; r < 4; ++r)
            out[HOFF + (size_t)(row0 + rb + r) * Hdim + j] = hreg[r];
    }

    // ---------------- decoder step 0 (real x[:,0,:], unfolded weights, prescaled) ----------------
    #pragma unroll
    for (int g = 0; g < 3; ++g) {
        float s = (g == 2) ? KN : KR;
        int n = g * Hdim + j;
        bwi[g] = load8s(dWih + n * Idim + kb, s);
        #pragma unroll
        for (int kk = 0; kk < 4; ++kk)
            bwh[g][kk] = load8s(dWhh + n * Hdim + kk * 32 + kb, s);
    }
    const float bihr = dBih[j],            bhhr = dBhh[j];
    const float bihz = dBih[Hdim + j],     bhhz = dBhh[Hdim + j];
    const float bihn = dBih[2 * Hdim + j], bhhn = dBhh[2 * Hdim + j];
    {
        float b0r = KR * (bihr + bhhr), b0z = KR * (bihz + bhhz);
        float b0i = KN * bihn,          b0h = KN * bhhn;
        arB = f32x4{b0r, b0r, b0r, b0r};
        azB = f32x4{b0z, b0z, b0z, b0z};
        aiB = f32x4{b0i, b0i, b0i, b0i};
        ahB = f32x4{b0h, b0h, b0h, b0h};
    }

    if (tid < 128) {
        float4 v = *(const float4*)(x + ((size_t)(row0 + srow) * Sdim + 0) * Idim + sc4);
        half4v hv;
        hv[0] = (_Float16)v.x; hv[1] = (_Float16)v.y; hv[2] = (_Float16)v.z; hv[3] = (_Float16)v.w;
        *(half4v*)&xlds[0][srow][sc4] = hv;
    }
    __syncthreads();
    {
        half8 ax  = *(const half8*)&xlds[0][cc][kb];
        half8 ah0 = *(const half8*)&hfrag[0][0][l * 8];
        half8 ah1 = *(const half8*)&hfrag[0][1][l * 8];
        half8 ah2 = *(const half8*)&hfrag[0][2][l * 8];
        half8 ah3 = *(const half8*)&hfrag[0][3][l * 8];

        f32x4 ar  = MFMA16(ax, bwi[0], arB);
        f32x4 az  = MFMA16(ax, bwi[1], azB);
        f32x4 ani = MFMA16(ax, bwi[2], aiB);
        f32x4 anh = ahB;
        #pragma unroll
        for (int m = 0; m < 4; ++m) {
            half8 ah = (m == 0) ? ah0 : (m == 1) ? ah1 : (m == 2) ? ah2 : ah3;
            ar  = MFMA16(ah, bwh[0][m], ar);
            az  = MFMA16(ah, bwh[1][m], az);
            anh = MFMA16(ah, bwh[2][m], anh);
        }
        #pragma unroll
        for (int r = 0; r < 4; ++r) {
            float hn = gru_h(ar[r], az[r], ani[r], anh[r], hreg[r]);
            hreg[r] = hn;
            hfrag[1][wm][wbase + (rb + r) * 8] = (_Float16)hn;
        }
        BARRIER();
    }
    __builtin_amdgcn_sched_barrier(0);

    // ---------------- folded decoder weights (prescaled) ----------------
    half8 bcr[4], bcz[4], bfn[4], bhn[4];
    #pragma unroll
    for (int m = 0; m < 4; ++m) {
        int ko = m * 32 + kb;
        bcr[m] = load8sum(ws + (size_t)j * Hdim + ko,          dWhh + (size_t)j * Hdim + ko, KR);
        bcz[m] = load8sum(ws + (size_t)(Hdim + j) * Hdim + ko, dWhh + (size_t)(Hdim + j) * Hdim + ko, KR);
        bfn[m] = load8s(ws + (size_t)(2 * Hdim + j) * Hdim + ko, KN);
        bhn[m] = load8s(dWhh + (size_t)(2 * Hdim + j) * Hdim + ko, KN);
    }
    const float* bx = ws + 3 * Hdim * Hdim;
    {
        float bdr = KR * (bihr + bhhr + bx[j]);
        float bdz = KR * (bihz + bhhz + bx[Hdim + j]);
        float bdi = KN * (bihn + bx[2 * Hdim + j]);
        float bdh = KN * bhhn;
        arB = f32x4{bdr, bdr, bdr, bdr};
        azB = f32x4{bdz, bdz, bdz, bdz};
        aiB = f32x4{bdi, bdi, bdi, bdi};
        ahB = f32x4{bdh, bdh, bdh, bdh};
    }

    half8 blin[4];
    float lb = 0.f;
    {
        half8 hz;
        #pragma unroll
        for (int e = 0; e < 8; ++e) hz[e] = (_Float16)0.f;
        blin[0] = hz; blin[1] = hz; blin[2] = hz; blin[3] = hz;
    }
    const int ycol = w * 16 + cc;      // in-range only for w<2
    if (w < 2) {
        #pragma unroll
        for (int kk = 0; kk < 4; ++kk)
            blin[kk] = load8s(linW + ycol * Hdim + kk * 32 + kb, 1.0f);
        lb = linB[ycol];
    }

    // ---------------- decoder scan t=1..S-1 (folded; y one step delayed) ----------------
    cur = 1;
    for (int t = 1; t < Sdim; ++t) {
        half8 ah0 = *(const half8*)&hfrag[cur][0][l * 8];
        half8 ah1 = *(const half8*)&hfrag[cur][1][l * 8];
        half8 ah2 = *(const half8*)&hfrag[cur][2][l * 8];
        half8 ah3 = *(const half8*)&hfrag[cur][3][l * 8];

        if (w < 2) {       // y_{t-1} = h_t @ linW^T + lb  (same A-frags, off critical path)
            f32x4 ay = MFMA16(ah0, blin[0], zero);
            ay = MFMA16(ah1, blin[1], ay);
            ay = MFMA16(ah2, blin[2], ay);
            ay = MFMA16(ah3, blin[3], ay);
            #pragma unroll
            for (int r = 0; r < 4; ++r)
                out[((size_t)(row0 + rb + r) * Sdim + (size_t)(t - 1)) * Idim + ycol] = ay[r] + lb;
        }

        f32x4 ar  = MFMA16(ah0, bcr[0], arB);
        f32x4 az  = MFMA16(ah0, bcz[0], azB);
        f32x4 ani = MFMA16(ah0, bfn[0], aiB);
        f32x4 anh = MFMA16(ah0, bhn[0], ahB);
        ar  = MFMA16(ah1, bcr[1], ar);
        az  = MFMA16(ah1, bcz[1], az);
        ani = MFMA16(ah1, bfn[1], ani);
        anh = MFMA16(ah1, bhn[1], anh);
        ar  = MFMA16(ah2, bcr[2], ar);
        az  = MFMA16(ah2, bcz[2], az);
        ani = MFMA16(ah2, bfn[2], ani);
        anh = MFMA16(ah2, bhn[2], anh);
        ar  = MFMA16(ah3, bcr[3], ar);
        az  = MFMA16(ah3, bcz[3], az);
        ani = MFMA16(ah3, bfn[3], ani);
        anh = MFMA16(ah3, bhn[3], anh);

        #pragma unroll
        for (int r = 0; r < 4; ++r) {
            float hn = gru_h(ar[r], az[r], ani[r], anh[r], hreg[r]);
            hreg[r] = hn;
            hfrag[cur ^ 1][wm][wbase + (rb + r) * 8] = (_Float16)hn;
        }
        BARRIER();
        cur ^= 1;
    }

    // final y_{S-1} from last h
    if (w < 2) {
        half8 ah0 = *(const half8*)&hfrag[cur][0][l * 8];
        half8 ah1 = *(const half8*)&hfrag[cur][1][l * 8];
        half8 ah2 = *(const half8*)&hfrag[cur][2][l * 8];
        half8 ah3 = *(const half8*)&hfrag[cur][3][l * 8];
        f32x4 ay = MFMA16(ah0, blin[0], zero);
        ay = MFMA16(ah1, blin[1], ay);
        ay = MFMA16(ah2, blin[2], ay);
        ay = MFMA16(ah3, blin[3], ay);
        #pragma unroll
        for (int r = 0; r < 4; ++r)
            out[((size_t)(row0 + rb + r) * Sdim + (size_t)(Sdim - 1)) * Idim + ycol] = ay[r] + lb;
    }
}

extern "C" void kernel_launch(void* const* d_in, const int* in_sizes, int n_in,
                              void* d_out, int out_size, void* d_ws, size_t ws_size,
                              hipStream_t stream) {
    (void)in_sizes; (void)n_in; (void)ws_size; (void)out_size;
    const float* x    = (const float*)d_in[0];
    const float* h0   = (const float*)d_in[1];
    const float* eWih = (const float*)d_in[2];
    const float* eWhh = (const float*)d_in[3];
    const float* eBih = (const float*)d_in[4];
    const float* eBhh = (const float*)d_in[5];
    const float* dWih = (const float*)d_in[6];
    const float* dWhh = (const float*)d_in[7];
    const float* dBih = (const float*)d_in[8];
    const float* dBhh = (const float*)d_in[9];
    const float* linW = (const float*)d_in[10];
    const float* linB = (const float*)d_in[11];
    float* ws = (float*)d_ws;

    fold_k<<<dim3((3 * Hdim * Hdim + 255) / 256), dim3(256), 0, stream>>>(dWih, linW, linB, ws);
    rnn_ae<<<dim3(Bdim / ROWS), dim3(THREADS), 0, stream>>>(
        x, h0, eWih, eWhh, eBih, eBhh, dWih, dWhh, dBih, dBhh, linW, linB,
        ws, (float*)d_out);
}

// Round 11
// 670.480 us; speedup vs baseline: 1.6388x; 1.0166x over previous
//
#include <hip/hip_runtime.h>

#define Hdim 128
#define Idim 32
#define Bdim 4096
#define Sdim 512
#define ROWS 16
#define THREADS 512
#define XPAD 40    // x row stride in halves (80B, 16B aligned)

#define KR (-1.44269504f)   // r,z prescale: Er = exp2(KR*arg) = e^-arg
#define KN (2.88539008f)    // n prescale:   En = exp2(KN*arg) = e^(2*arg)

typedef _Float16 half8 __attribute__((ext_vector_type(8)));
typedef _Float16 half4v __attribute__((ext_vector_type(4)));
typedef float f32x4 __attribute__((ext_vector_type(4)));

#define MFMA16(a, b, c) __builtin_amdgcn_mfma_f32_16x16x32_f16((a), (b), (c), 0, 0, 0)

// LDS-only barrier: no vmcnt drain (x loads covered by register deps, y stores never read).
#define BARRIER() asm volatile("s_waitcnt lgkmcnt(0)\n\ts_barrier" ::: "memory")

// Fused GRU update on 4 elements, paired-rcp: 16 trans/4 elems (was 20).
// All exp2 args clamped at 30 so paired products stay finite (den<=2^60, pair<=2^120).
__device__ __forceinline__ void gru_h4(const f32x4& ar, const f32x4& az,
                                       const f32x4& ani, const f32x4& anh,
                                       float* h) {
    float er[4], ez[4], sr[4], R[4], en[4], num[4], den[4];
    #pragma unroll
    for (int r = 0; r < 4; ++r) {
        er[r] = __builtin_amdgcn_exp2f(fminf(ar[r], 30.f));  // e^-rarg
        ez[r] = __builtin_amdgcn_exp2f(fminf(az[r], 30.f));  // e^-zarg
        sr[r] = 1.f + er[r];
    }
    float rp0 = __builtin_amdgcn_rcpf(sr[0] * sr[1]);        // shared rcp (pair 0,1)
    float rp1 = __builtin_amdgcn_rcpf(sr[2] * sr[3]);        // shared rcp (pair 2,3)
    R[0] = rp0 * sr[1]; R[1] = rp0 * sr[0];                  // sigmoid(rarg)
    R[2] = rp1 * sr[3]; R[3] = rp1 * sr[2];
    #pragma unroll
    for (int r = 0; r < 4; ++r) {
        en[r]  = __builtin_amdgcn_exp2f(fminf(fmaf(R[r], anh[r], ani[r]), 30.f)); // e^(2*narg)
        num[r] = fmaf(en[r], ez[r] + h[r], h[r] - ez[r]);    // En(Ez+h) + (h-Ez)
        den[r] = (1.f + ez[r]) * (1.f + en[r]);
    }
    float q0 = __builtin_amdgcn_rcpf(den[0] * den[1]);       // shared rcp (pair 0,1)
    float q1 = __builtin_amdgcn_rcpf(den[2] * den[3]);       // shared rcp (pair 2,3)
    h[0] = num[0] * den[1] * q0;                             // (1-z)*tanh(narg) + z*h
    h[1] = num[1] * den[0] * q0;
    h[2] = num[2] * den[3] * q1;
    h[3] = num[3] * den[2] * q1;
}

__device__ __forceinline__ half8 load8s(const float* __restrict__ p, float s) {
    float4 a = *(const float4*)p;
    float4 b = *(const float4*)(p + 4);
    half8 r;
    r[0] = (_Float16)(a.x * s); r[1] = (_Float16)(a.y * s);
    r[2] = (_Float16)(a.z * s); r[3] = (_Float16)(a.w * s);
    r[4] = (_Float16)(b.x * s); r[5] = (_Float16)(b.y * s);
    r[6] = (_Float16)(b.z * s); r[7] = (_Float16)(b.w * s);
    return r;
}
// f16(s*(a[k] + b[k])) for 8 elements (combined decoder weights)
__device__ __forceinline__ half8 load8sum(const float* __restrict__ a, const float* __restrict__ b, float s) {
    float4 a0 = *(const float4*)a,     a1 = *(const float4*)(a + 4);
    float4 b0 = *(const float4*)b,     b1 = *(const float4*)(b + 4);
    half8 r;
    r[0] = (_Float16)((a0.x + b0.x) * s); r[1] = (_Float16)((a0.y + b0.y) * s);
    r[2] = (_Float16)((a0.z + b0.z) * s); r[3] = (_Float16)((a0.w + b0.w) * s);
    r[4] = (_Float16)((a1.x + b1.x) * s); r[5] = (_Float16)((a1.y + b1.y) * s);
    r[6] = (_Float16)((a1.z + b1.z) * s); r[7] = (_Float16)((a1.w + b1.w) * s);
    return r;
}

// ---- prep: Wfold[n][h] = sum_i dWih[n][i]*linW[i][h]; bx[n] = sum_i dWih[n][i]*lin_b[i]
extern "C" __global__ void fold_k(const float* __restrict__ dWih, const float* __restrict__ linW,
                                  const float* __restrict__ linB, float* __restrict__ ws) {
    int idx = blockIdx.x * 256 + threadIdx.x;
    if (idx < 3 * Hdim * Hdim) {
        int n = idx >> 7, h = idx & 127;
        float s = 0.f;
        #pragma unroll
        for (int i = 0; i < Idim; ++i) s += dWih[n * Idim + i] * linW[i * Hdim + h];
        ws[idx] = s;
    }
    if (idx < 3 * Hdim) {
        float s = 0.f;
        #pragma unroll
        for (int i = 0; i < Idim; ++i) s += dWih[idx * Idim + i] * linB[i];
        ws[3 * Hdim * Hdim + idx] = s;
    }
}

extern "C" __global__ __launch_bounds__(THREADS, 2)
void rnn_ae(const float* __restrict__ x, const float* __restrict__ h0,
            const float* __restrict__ eWih, const float* __restrict__ eWhh,
            const float* __restrict__ eBih, const float* __restrict__ eBhh,
            const float* __restrict__ dWih, const float* __restrict__ dWhh,
            const float* __restrict__ dBih, const float* __restrict__ dBhh,
            const float* __restrict__ linW, const float* __restrict__ linB,
            const float* __restrict__ ws, float* __restrict__ out)
{
    // h stored in MFMA-A-fragment order: region m (k-tile), lane l reads halves [l*8, l*8+8)
    __shared__ _Float16 hfrag[2][4][512];
    __shared__ _Float16 xlds[2][ROWS][XPAD];

    const int tid = threadIdx.x;
    const int w   = tid >> 6;          // wave 0..7 -> hidden-col slice [16w,16w+16)
    const int l   = tid & 63;
    const int cc  = l & 15;            // A-row / B-col / C-col lane field
    const int cq  = l >> 4;            // quad 0..3
    const int kb  = cq * 8;            // A/B k-base
    const int rb  = cq * 4;            // C row-base (batch rows)
    const int row0 = blockIdx.x * ROWS;
    const int j   = w * 16 + cc;       // this lane's hidden/gate column
    const int srow = tid >> 3;         // staging row (tid<128)
    const int sc4  = (tid & 7) << 2;   // staging col
    const int wm   = j >> 5;                            // h-write frag region
    const int wbase = ((j & 31) >> 3) * 128 + (j & 7);  // h-write halves base in region

    const f32x4 zero = {0.f, 0.f, 0.f, 0.f};

    // ---------------- encoder weights -> registers (prescaled) ----------------
    half8 bwi[3], bwh[3][4];
    #pragma unroll
    for (int g = 0; g < 3; ++g) {
        float s = (g == 2) ? KN : KR;
        int n = g * Hdim + j;                          // gate row in [3H] (r,z,n order)
        bwi[g] = load8s(eWih + n * Idim + kb, s);      // B[k][n] = W[n][k]
        #pragma unroll
        for (int kk = 0; kk < 4; ++kk)
            bwh[g][kk] = load8s(eWhh + n * Hdim + kk * 32 + kb, s);
    }
    // bias-in-accumulator vectors
    float brv  = KR * (eBih[j] + eBhh[j]);
    float bzv  = KR * (eBih[Hdim + j] + eBhh[Hdim + j]);
    float bniv = KN * eBih[2 * Hdim + j];
    float bnhv = KN * eBhh[2 * Hdim + j];
    f32x4 arB = {brv, brv, brv, brv};
    f32x4 azB = {bzv, bzv, bzv, bzv};
    f32x4 aiB = {bniv, bniv, bniv, bniv};
    f32x4 ahB = {bnhv, bnhv, bnhv, bnhv};

    float hreg[4];
    #pragma unroll
    for (int r = 0; r < 4; ++r) {
        hreg[r] = h0[(size_t)(row0 + rb + r) * Hdim + j];
        hfrag[0][wm][wbase + (rb + r) * 8] = (_Float16)hreg[r];
    }

    // x pipeline prologue: x[0] -> xlds[0]; x[1] -> regs (xv); xp -> x[2]
    const float* xp = x + (size_t)(row0 + srow) * Sdim * Idim + sc4;
    float4 xv = {0.f, 0.f, 0.f, 0.f};
    if (tid < 128) {
        float4 v = *(const float4*)xp;
        half4v hv;
        hv[0] = (_Float16)v.x; hv[1] = (_Float16)v.y; hv[2] = (_Float16)v.z; hv[3] = (_Float16)v.w;
        *(half4v*)&xlds[0][srow][sc4] = hv;
        xv = *(const float4*)(xp + Idim);
    }
    xp += 2 * Idim;
    __syncthreads();

    // ---------------- encoder scan ----------------
    int cur = 0;
    for (int t = 0; t < Sdim; ++t) {
        half8 ax  = *(const half8*)&xlds[cur][cc][kb];
        half8 ah0 = *(const half8*)&hfrag[cur][0][l * 8];
        half8 ah1 = *(const half8*)&hfrag[cur][1][l * 8];
        half8 ah2 = *(const half8*)&hfrag[cur][2][l * 8];
        half8 ah3 = *(const half8*)&hfrag[cur][3][l * 8];

        if (tid < 128) {
            if (t + 1 < Sdim) {
                half4v hv;
                hv[0] = (_Float16)xv.x; hv[1] = (_Float16)xv.y;
                hv[2] = (_Float16)xv.z; hv[3] = (_Float16)xv.w;
                *(half4v*)&xlds[cur ^ 1][srow][sc4] = hv;
            }
            if (t + 2 < Sdim)
                xv = *(const float4*)xp;
        }
        xp += Idim;

        f32x4 ar  = MFMA16(ax, bwi[0], arB);
        f32x4 az  = MFMA16(ax, bwi[1], azB);
        f32x4 ani = MFMA16(ax, bwi[2], aiB);
        f32x4 anh = ahB;
        ar  = MFMA16(ah0, bwh[0][0], ar);
        ar  = MFMA16(ah1, bwh[0][1], ar);
        ar  = MFMA16(ah2, bwh[0][2], ar);
        ar  = MFMA16(ah3, bwh[0][3], ar);
        az  = MFMA16(ah0, bwh[1][0], az);
        az  = MFMA16(ah1, bwh[1][1], az);
        az  = MFMA16(ah2, bwh[1][2], az);
        az  = MFMA16(ah3, bwh[1][3], az);
        anh = MFMA16(ah0, bwh[2][0], anh);
        anh = MFMA16(ah1, bwh[2][1], anh);
        anh = MFMA16(ah2, bwh[2][2], anh);
        anh = MFMA16(ah3, bwh[2][3], anh);

        gru_h4(ar, az, ani, anh, hreg);
        #pragma unroll
        for (int r = 0; r < 4; ++r)
            hfrag[cur ^ 1][wm][wbase + (rb + r) * 8] = (_Float16)hreg[r];

        BARRIER();
        cur ^= 1;
    }
    // cur == 0 here; hfrag[0] holds h_enc

    // encoder final hidden -> output tail
    {
        const size_t HOFF = (size_t)Bdim * Sdim * Idim;
        #pragma unroll
        for (int r = 0; r < 4; ++r)
            out[HOFF + (size_t)(row0 + rb + r) * Hdim + j] = hreg[r];
    }

    // ---------------- decoder step 0 (real x[:,0,:], unfolded weights, prescaled) ----------------
    #pragma unroll
    for (int g = 0; g < 3; ++g) {
        float s = (g == 2) ? KN : KR;
        int n = g * Hdim + j;
        bwi[g] = load8s(dWih + n * Idim + kb, s);
        #pragma unroll
        for (int kk = 0; kk < 4; ++kk)
            bwh[g][kk] = load8s(dWhh + n * Hdim + kk * 32 + kb, s);
    }
    const float bihr = dBih[j],            bhhr = dBhh[j];
    const float bihz = dBih[Hdim + j],     bhhz = dBhh[Hdim + j];
    const float bihn = dBih[2 * Hdim + j], bhhn = dBhh[2 * Hdim + j];
    {
        float b0r = KR * (bihr + bhhr), b0z = KR * (bihz + bhhz);
        float b0i = KN * bihn,          b0h = KN * bhhn;
        arB = f32x4{b0r, b0r, b0r, b0r};
        azB = f32x4{b0z, b0z, b0z, b0z};
        aiB = f32x4{b0i, b0i, b0i, b0i};
        ahB = f32x4{b0h, b0h, b0h, b0h};
    }

    if (tid < 128) {
        float4 v = *(const float4*)(x + (size_t)(row0 + srow) * Sdim * Idim + sc4);
        half4v hv;
        hv[0] = (_Float16)v.x; hv[1] = (_Float16)v.y; hv[2] = (_Float16)v.z; hv[3] = (_Float16)v.w;
        *(half4v*)&xlds[0][srow][sc4] = hv;
    }
    __syncthreads();
    {
        half8 ax  = *(const half8*)&xlds[0][cc][kb];
        half8 ah0 = *(const half8*)&hfrag[0][0][l * 8];
        half8 ah1 = *(const half8*)&hfrag[0][1][l * 8];
        half8 ah2 = *(const half8*)&hfrag[0][2][l * 8];
        half8 ah3 = *(const half8*)&hfrag[0][3][l * 8];

        f32x4 ar  = MFMA16(ax, bwi[0], arB);
        f32x4 az  = MFMA16(ax, bwi[1], azB);
        f32x4 ani = MFMA16(ax, bwi[2], aiB);
        f32x4 anh = ahB;
        #pragma unroll
        for (int m = 0; m < 4; ++m) {
            half8 ah = (m == 0) ? ah0 : (m == 1) ? ah1 : (m == 2) ? ah2 : ah3;
            ar  = MFMA16(ah, bwh[0][m], ar);
            az  = MFMA16(ah, bwh[1][m], az);
            anh = MFMA16(ah, bwh[2][m], anh);
        }
        gru_h4(ar, az, ani, anh, hreg);
        #pragma unroll
        for (int r = 0; r < 4; ++r)
            hfrag[1][wm][wbase + (rb + r) * 8] = (_Float16)hreg[r];
        BARRIER();
    }
    __builtin_amdgcn_sched_barrier(0);

    // ---------------- folded decoder weights (prescaled) ----------------
    half8 bcr[4], bcz[4], bfn[4], bhn[4];
    #pragma unroll
    for (int m = 0; m < 4; ++m) {
        int ko = m * 32 + kb;
        bcr[m] = load8sum(ws + (size_t)j * Hdim + ko,          dWhh + (size_t)j * Hdim + ko, KR);
        bcz[m] = load8sum(ws + (size_t)(Hdim + j) * Hdim + ko, dWhh + (size_t)(Hdim + j) * Hdim + ko, KR);
        bfn[m] = load8s(ws + (size_t)(2 * Hdim + j) * Hdim + ko, KN);
        bhn[m] = load8s(dWhh + (size_t)(2 * Hdim + j) * Hdim + ko, KN);
    }
    const float* bx = ws + 3 * Hdim * Hdim;
    {
        float bdr = KR * (bihr + bhhr + bx[j]);
        float bdz = KR * (bihz + bhhz + bx[Hdim + j]);
        float bdi = KN * (bihn + bx[2 * Hdim + j]);
        float bdh = KN * bhhn;
        arB = f32x4{bdr, bdr, bdr, bdr};
        azB = f32x4{bdz, bdz, bdz, bdz};
        aiB = f32x4{bdi, bdi, bdi, bdi};
        ahB = f32x4{bdh, bdh, bdh, bdh};
    }

    half8 blin[4];
    float lb = 0.f;
    {
        half8 hz;
        #pragma unroll
        for (int e = 0; e < 8; ++e) hz[e] = (_Float16)0.f;
        blin[0] = hz; blin[1] = hz; blin[2] = hz; blin[3] = hz;
    }
    const int ycol = w * 16 + cc;      // in-range only for w<2
    if (w < 2) {
        #pragma unroll
        for (int kk = 0; kk < 4; ++kk)
            blin[kk] = load8s(linW + ycol * Hdim + kk * 32 + kb, 1.0f);
        lb = linB[ycol];
    }
    float* yp = out + (size_t)(row0 + rb) * Sdim * Idim + ycol;  // y[row0+rb][t=0][ycol]
    const size_t YROW = (size_t)Sdim * Idim;

    // ---------------- decoder scan t=1..S-1 (folded; y one step delayed) ----------------
    cur = 1;
    for (int t = 1; t < Sdim; ++t) {
        half8 ah0 = *(const half8*)&hfrag[cur][0][l * 8];
        half8 ah1 = *(const half8*)&hfrag[cur][1][l * 8];
        half8 ah2 = *(const half8*)&hfrag[cur][2][l * 8];
        half8 ah3 = *(const half8*)&hfrag[cur][3][l * 8];

        if (w < 2) {       // y_{t-1} = h_t @ linW^T + lb  (same A-frags, off critical path)
            f32x4 ay = MFMA16(ah0, blin[0], zero);
            ay = MFMA16(ah1, blin[1], ay);
            ay = MFMA16(ah2, blin[2], ay);
            ay = MFMA16(ah3, blin[3], ay);
            #pragma unroll
            for (int r = 0; r < 4; ++r)
                yp[r * YROW] = ay[r] + lb;
        }
        yp += Idim;

        f32x4 ar  = MFMA16(ah0, bcr[0], arB);
        f32x4 az  = MFMA16(ah0, bcz[0], azB);
        f32x4 ani = MFMA16(ah0, bfn[0], aiB);
        f32x4 anh = MFMA16(ah0, bhn[0], ahB);
        ar  = MFMA16(ah1, bcr[1], ar);
        az  = MFMA16(ah1, bcz[1], az);
        ani = MFMA16(ah1, bfn[1], ani);
        anh = MFMA16(ah1, bhn[1], anh);
        ar  = MFMA16(ah2, bcr[2], ar);
        az  = MFMA16(ah2, bcz[2], az);
        ani = MFMA16(ah2, bfn[2], ani);
        anh = MFMA16(ah2, bhn[2], anh);
        ar  = MFMA16(ah3, bcr[3], ar);
        az  = MFMA16(ah3, bcz[3], az);
        ani = MFMA16(ah3, bfn[3], ani);
        anh = MFMA16(ah3, bhn[3], anh);

        gru_h4(ar, az, ani, anh, hreg);
        #pragma unroll
        for (int r = 0; r < 4; ++r)
            hfrag[cur ^ 1][wm][wbase + (rb + r) * 8] = (_Float16)hreg[r];

        BARRIER();
        cur ^= 1;
    }

    // final y_{S-1} from last h
    if (w < 2) {
        half8 ah0 = *(const half8*)&hfrag[cur][0][l * 8];
        half8 ah1 = *(const half8*)&hfrag[cur][1][l * 8];
        half8 ah2 = *(const half8*)&hfrag[cur][2][l * 8];
        half8 ah3 = *(const half8*)&hfrag[cur][3][l * 8];
        f32x4 ay = MFMA16(ah0, blin[0], zero);
        ay = MFMA16(ah1, blin[1], ay);
        ay = MFMA16(ah2, blin[2], ay);
        ay = MFMA16(ah3, blin[3], ay);
        #pragma unroll
        for (int r = 0; r < 4; ++r)
            yp[r * YROW] = ay[r] + lb;
    }
}

extern "C" void kernel_launch(void* const* d_in, const int* in_sizes, int n_in,
                              void* d_out, int out_size, void* d_ws, size_t ws_size,
                              hipStream_t stream) {
    (void)in_sizes; (void)n_in; (void)ws_size; (void)out_size;
    const float* x    = (const float*)d_in[0];
    const float* h0   = (const float*)d_in[1];
    const float* eWih = (const float*)d_in[2];
    const float* eWhh = (const float*)d_in[3];
    const float* eBih = (const float*)d_in[4];
    const float* eBhh = (const float*)d_in[5];
    const float* dWih = (const float*)d_in[6];
    const float* dWhh = (const float*)d_in[7];
    const float* dBih = (const float*)d_in[8];
    const float* dBhh = (const float*)d_in[9];
    const float* linW = (const float*)d_in[10];
    const float* linB = (const float*)d_in[11];
    float* ws = (float*)d_ws;

    fold_k<<<dim3((3 * Hdim * Hdim + 255) / 256), dim3(256), 0, stream>>>(dWih, linW, linB, ws);
    rnn_ae<<<dim3(Bdim / ROWS), dim3(THREADS), 0, stream>>>(
        x, h0, eWih, eWhh, eBih, eBhh, dWih, dWhh, dBih, dBhh, linW, linB,
        ws, (float*)d_out);
}